// Round 1
// baseline (632.526 us; speedup 1.0000x reference)
//
#include <hip/hip_runtime.h>
#include <hip/hip_bf16.h>
#include <math.h>

typedef __attribute__((ext_vector_type(8))) short bf16x8;
typedef __attribute__((ext_vector_type(4))) float f32x4;

#define FRAME_PAD (66*66*128)   // padded NHWC frame elems (557568)

#define GLOAD_LDS16(g, l) \
    __builtin_amdgcn_global_load_lds((const __attribute__((address_space(1))) void*)(g), \
                                     (__attribute__((address_space(3))) void*)(l), 16, 0, 0)

__device__ __forceinline__ float sigmoidf_(float x) { return 1.0f / (1.0f + expf(-x)); }

// ---------- weight transform: W[oc][ic][ky][kx] f32 -> Wt[tap][oc][ic] bf16 ----------
__global__ void wt_kernel(const float* __restrict__ w, __hip_bfloat16* __restrict__ wt)
{
    int idx = blockIdx.x * 256 + threadIdx.x;
    if (idx >= 9 * 512 * 256) return;
    int ic  = idx & 255;
    int oc  = (idx >> 8) & 511;
    int tap = idx >> 17;
    wt[idx] = __float2bfloat16(w[((size_t)oc * 256 + (size_t)ic) * 9 + tap]);
}

// ---------- x: NCHW f32 -> padded NHWC bf16 (border pre-zeroed by memset) ----------
__global__ void xpose_kernel(const float* __restrict__ x, __hip_bfloat16* __restrict__ x_pad)
{
    __shared__ float tile[128][65];
    const int f = blockIdx.x >> 6;
    const int y = blockIdx.x & 63;
    const int tid = threadIdx.x;
    const float* src = x + (size_t)f * 524288 + (size_t)y * 64;
    #pragma unroll
    for (int it = 0; it < 32; ++it) {
        int c  = it * 4 + (tid >> 6);
        int xc = tid & 63;
        tile[c][xc] = src[(size_t)c * 4096 + xc];
    }
    __syncthreads();
    __hip_bfloat16* dst = x_pad + (size_t)f * FRAME_PAD + (size_t)((y + 1) * 66 + 1) * 128;
    #pragma unroll
    for (int it = 0; it < 16; ++it) {
        int xr = it * 4 + (tid >> 6);
        int c2 = (tid & 63) * 2;
        __hip_bfloat162 v;
        v.x = __float2bfloat16(tile[c2][xr]);
        v.y = __float2bfloat16(tile[c2 + 1][xr]);
        *(__hip_bfloat162*)(dst + (size_t)xr * 128 + c2) = v;
    }
}

// ---------- implicit-GEMM conv: z[m][n] = sum_k A[m,k] * B[k,n] ----------
// m = b*4096 + y*64 + x (per-step spatial, 16384), n = out channel (512),
// k = tap*256 + ic; ic<128 from x_pad frame (b*8+t), ic>=128 from h_pad frame (b*9+t).
__global__ __launch_bounds__(256)
void conv_gemm(const __hip_bfloat16* __restrict__ x_pad,
               const __hip_bfloat16* __restrict__ h_pad,
               const __hip_bfloat16* __restrict__ wt,
               float* __restrict__ z, int t)
{
    __shared__ alignas(16) __hip_bfloat16 As[128 * 32];
    __shared__ alignas(16) __hip_bfloat16 Bs[128 * 32];
    const int tid  = threadIdx.x;
    const int wv   = tid >> 6;
    const int lane = tid & 63;
    const int n0   = blockIdx.x * 128;
    const int mblk = blockIdx.y;
    const int b    = mblk >> 5;
    const int y0   = (mblk & 31) * 2;
    const int m0   = mblk * 128;

    const __hip_bfloat16* xf = x_pad + (size_t)(b * 8 + t) * FRAME_PAD;
    const __hip_bfloat16* hf = h_pad + (size_t)(b * 9 + t) * FRAME_PAD;

    int offA[2], offB[2];
    #pragma unroll
    for (int i = 0; i < 2; ++i) {
        int slot = i * 256 + tid;
        int row  = slot >> 2;
        int q    = slot & 3;
        offA[i] = ((y0 + (row >> 6)) * 66 + (row & 63)) * 128 + q * 8;
        offB[i] = (n0 + row) * 256 + q * 8;
    }
    __hip_bfloat16* ldsA[2] = { As + (size_t)(wv * 64) * 8, As + (size_t)(256 + wv * 64) * 8 };
    __hip_bfloat16* ldsB[2] = { Bs + (size_t)(wv * 64) * 8, Bs + (size_t)(256 + wv * 64) * 8 };

    f32x4 acc[4][4] = {};
    const int wm = wv >> 1, wn = wv & 1;
    const int fr = lane & 15, fq = lane >> 4;
    const int aRow0 = (wm * 64 + fr) * 32 + fq * 8;
    const int bRow0 = (wn * 64 + fr) * 32 + fq * 8;

    for (int kk = 0; kk < 72; ++kk) {
        const int tap  = kk >> 3;
        const int koff = (kk & 7) * 32;
        const int dy = tap / 3, dx = tap % 3;
        const __hip_bfloat16* src;
        int ch;
        if (koff < 128) { src = xf; ch = koff; }
        else            { src = hf; ch = koff - 128; }
        const int adda = (dy * 66 + dx) * 128 + ch;
        const int addb = tap * 131072 + koff;
        #pragma unroll
        for (int i = 0; i < 2; ++i) GLOAD_LDS16(src + adda + offA[i], ldsA[i]);
        #pragma unroll
        for (int i = 0; i < 2; ++i) GLOAD_LDS16(wt + addb + offB[i], ldsB[i]);
        __syncthreads();

        #pragma unroll
        for (int mi = 0; mi < 4; ++mi) {
            bf16x8 a = *(const bf16x8*)(As + aRow0 + mi * (16 * 32));
            #pragma unroll
            for (int ni = 0; ni < 4; ++ni) {
                bf16x8 bb = *(const bf16x8*)(Bs + bRow0 + ni * (16 * 32));
                acc[mi][ni] = __builtin_amdgcn_mfma_f32_16x16x32_bf16(a, bb, acc[mi][ni], 0, 0, 0);
            }
        }
        __syncthreads();
    }

    #pragma unroll
    for (int mi = 0; mi < 4; ++mi) {
        const int mg = m0 + wm * 64 + mi * 16 + fq * 4;
        #pragma unroll
        for (int ni = 0; ni < 4; ++ni) {
            const int ng = n0 + wn * 64 + ni * 16 + fr;
            float* zp = z + (size_t)mg * 512 + ng;
            #pragma unroll
            for (int r = 0; r < 4; ++r) zp[(size_t)r * 512] = acc[mi][ni][r];
        }
    }
}

// ---------- gates: z -> (c_state, h) ; h written padded-NHWC bf16 for next conv ----------
__global__ void gate_kernel(const float* __restrict__ z, const float* __restrict__ bias,
                            float* __restrict__ c_state, __hip_bfloat16* __restrict__ h_pad,
                            int t)
{
    const int idx = blockIdx.x * 256 + threadIdx.x;
    const int c = idx & 127;
    const int m = idx >> 7;
    const int b = m >> 12;
    const int s = m & 4095;
    const size_t zb = (size_t)m * 512 + c;
    float zi = z[zb]       + bias[c];
    float zf = z[zb + 128] + bias[c + 128];
    float zo = z[zb + 256] + bias[c + 256];
    float zg = z[zb + 384] + bias[c + 384];
    float cold = c_state[idx];
    float cn = sigmoidf_(zf) * cold + sigmoidf_(zi) * tanhf(zg);
    float h  = sigmoidf_(zo) * tanhf(cn);
    c_state[idx] = cn;
    const int yy = (s >> 6) + 1, xx = (s & 63) + 1;
    h_pad[(size_t)(b * 9 + t + 1) * FRAME_PAD + (size_t)(yy * 66 + xx) * 128 + c] =
        __float2bfloat16(h);
}

// ---------- final: padded-NHWC bf16 h -> NCHW f32 out with BN(eval)+ReLU ----------
__global__ void bn_out_kernel(const __hip_bfloat16* __restrict__ h_pad,
                              const float* __restrict__ gamma, const float* __restrict__ beta,
                              const float* __restrict__ rmean, const float* __restrict__ rvar,
                              float* __restrict__ out)
{
    __shared__ float tile[64][130];
    __shared__ float sc_s[128], sh_s[128];
    const int fo  = blockIdx.x >> 6;
    const int y   = blockIdx.x & 63;
    const int tid = threadIdx.x;
    if (tid < 128) {
        float sc = gamma[tid] * rsqrtf(rvar[tid] + 1e-5f);
        sc_s[tid] = sc;
        sh_s[tid] = beta[tid] - rmean[tid] * sc;
    }
    const int b = fo >> 3, t = fo & 7;
    const __hip_bfloat16* src =
        h_pad + (size_t)(b * 9 + 1 + t) * FRAME_PAD + (size_t)((y + 1) * 66 + 1) * 128;
    #pragma unroll
    for (int it = 0; it < 32; ++it) {
        int xr = it * 2 + (tid >> 7);
        int c  = tid & 127;
        tile[xr][c] = __bfloat162float(src[(size_t)xr * 128 + c]);
    }
    __syncthreads();
    float* dst = out + (size_t)fo * 524288 + (size_t)y * 64;
    #pragma unroll
    for (int it = 0; it < 32; ++it) {
        int c  = it * 4 + (tid >> 6);
        int xc = tid & 63;
        float v = tile[xc][c] * sc_s[c] + sh_s[c];
        dst[(size_t)c * 4096 + xc] = fmaxf(v, 0.0f);
    }
}

extern "C" void kernel_launch(void* const* d_in, const int* in_sizes, int n_in,
                              void* d_out, int out_size, void* d_ws, size_t ws_size,
                              hipStream_t stream)
{
    const float* x      = (const float*)d_in[0];
    const float* w_conv = (const float*)d_in[1];
    const float* b_conv = (const float*)d_in[2];
    const float* gamma  = (const float*)d_in[3];
    const float* beta   = (const float*)d_in[4];
    const float* rmean  = (const float*)d_in[5];
    const float* rvar   = (const float*)d_in[6];
    float* out = (float*)d_out;

    // workspace layout (bytes)
    //   Wt      @ 0          : 9*512*256*2        = 2,359,296
    //   x_pad   @ 2359296    : 32*66*66*128*2     = 35,684,352
    //   h_pad   @ 38043648   : 36*66*66*128*2     = 40,144,896  (slot b*9+0 = zeros)
    //   c_state @ 78188544   : 4*4096*128*4       = 8,388,608
    //   z_buf   @ 86577152   : 16384*512*4        = 33,554,432
    //   total 120,131,584
    if (ws_size < 120131584u) return;  // diagnostic: absmax will be exactly max|ref|

    char* ws = (char*)d_ws;
    __hip_bfloat16* Wt    = (__hip_bfloat16*)(ws);
    __hip_bfloat16* x_pad = (__hip_bfloat16*)(ws + 2359296);
    __hip_bfloat16* h_pad = (__hip_bfloat16*)(ws + 38043648);
    float* c_state        = (float*)(ws + 78188544);
    float* z_buf          = (float*)(ws + 86577152);

    hipMemsetAsync(x_pad, 0, 35684352, stream);
    hipMemsetAsync(h_pad, 0, 40144896, stream);
    hipMemsetAsync(c_state, 0, 8388608, stream);

    wt_kernel<<<4608, 256, 0, stream>>>(w_conv, Wt);
    xpose_kernel<<<2048, 256, 0, stream>>>(x, x_pad);

    for (int t = 0; t < 8; ++t) {
        conv_gemm<<<dim3(4, 128), 256, 0, stream>>>(x_pad, h_pad, Wt, z_buf, t);
        gate_kernel<<<8192, 256, 0, stream>>>(z_buf, b_conv, c_state, h_pad, t);
    }
    bn_out_kernel<<<2048, 256, 0, stream>>>(h_pad, gamma, beta, rmean, rvar, out);
}